// Round 1
// baseline (63.954 us; speedup 1.0000x reference)
//
#include <hip/hip_runtime.h>
#include <math.h>

#define NC   80
#define BS   16
#define NOBJ 32

__device__ __forceinline__ float softplusf(float x) {
    // stable log(1+exp(x)) == max(x,0) + log1p(exp(-|x|))  (matches jax.nn.softplus)
    return fmaxf(x, 0.0f) + log1pf(expf(-fabsf(x)));
}

__global__ void __launch_bounds__(256)
yolo_loss_kernel(const float* __restrict__ p0,
                 const float* __restrict__ p1,
                 const float* __restrict__ p2,
                 const float* __restrict__ gtb,   // (16,32,4) f32
                 const int*   __restrict__ gtc,   // (16,32) i32
                 float* __restrict__ out)
{
    const float* ps[3] = {p0, p1, p2};
    const int    hs[3] = {80, 40, 20};

    const int cells0 = BS * 80 * 80;            // 102400
    const int cells1 = BS * 40 * 40;            // 25600
    const int cells2 = BS * 20 * 20;            // 6400
    const int totalCells = cells0 + cells1 + cells2;  // 134400
    const int totalObj   = 3 * BS * NOBJ;             // 1536
    const int total      = totalCells + totalObj;

    float acc = 0.0f;

    for (int i = blockIdx.x * blockDim.x + threadIdx.x; i < total;
         i += gridDim.x * blockDim.x) {
        if (i < totalCells) {
            // ---- lobj baseline over the whole grid (t = 0 everywhere) ----
            int idx = i, s;
            if (idx < cells0)                { s = 0; }
            else if (idx < cells0 + cells1)  { s = 1; idx -= cells0; }
            else                             { s = 2; idx -= cells0 + cells1; }
            const int h  = hs[s];
            const int hw = h * h;
            const int b  = idx / hw;
            const int r  = idx - b * hw;
            const float* p = ps[s];
            const size_t base = (size_t)b * 144 * hw + r;
            float m = 0.25f * (p[base] + p[base + hw] +
                               p[base + 2 * (size_t)hw] + p[base + 3 * (size_t)hw]);
            float po  = 1.0f / (1.0f + expf(-m));
            float inv = 1.0f / (float)(BS * hw);
            acc += (1.0f / 3.0f) * po * po * inv;
        } else {
            // ---- per-object: lbox + lcls + lobj correction at marked cells ----
            int oi  = i - totalCells;
            int s   = oi / (BS * NOBJ);
            int rem = oi - s * (BS * NOBJ);
            int b   = rem / NOBJ;
            int o   = rem - b * NOBJ;
            const int h  = hs[s];
            const int w  = h;
            const int hw = h * w;
            const float* p = ps[s];
            const float* g = gtb + ((size_t)b * NOBJ + o) * 4;
            float cx = g[0] * w, cy = g[1] * h, gw = g[2] * w, gh = g[3] * h;
            int gx = min(max((int)cx, 0), w - 1);
            int gy = min(max((int)cy, 0), h - 1);
            const size_t cell = (size_t)b * 144 * hw + (size_t)gy * w + gx;

            // lbox: mean over 4 of (pred - target)^2
            float bt0 = cx - (float)gx;
            float bt1 = cy - (float)gy;
            float bt2 = gw / (float)w;
            float bt3 = gh / (float)h;
            float c0 = p[cell];
            float c1 = p[cell + hw];
            float c2 = p[cell + 2 * (size_t)hw];
            float c3 = p[cell + 3 * (size_t)hw];
            float d0 = c0 - bt0, d1 = c1 - bt1, d2 = c2 - bt2, d3 = c3 - bt3;
            acc += (7.5f / 3.0f) * 0.25f * (d0*d0 + d1*d1 + d2*d2 + d3*d3);

            // lcls: mean over 80 of softplus(x) - x*onehot
            int cls = gtc[b * NOBJ + o];
            float lc = 0.0f;
            for (int c = 0; c < NC; ++c) {
                float x = p[cell + (size_t)(64 + c) * hw];
                lc += softplusf(x);
                if (c == cls) lc -= x;
            }
            acc += (0.5f / 3.0f) * (lc / (float)NC);

            // lobj correction: only the FIRST object hitting this cell counts
            // (reference .set(1.0) scatter is idempotent across duplicates)
            bool first = true;
            for (int j = 0; j < o; ++j) {
                const float* gj = gtb + ((size_t)b * NOBJ + j) * 4;
                int gxj = min(max((int)(gj[0] * w), 0), w - 1);
                int gyj = min(max((int)(gj[1] * h), 0), h - 1);
                if (gxj == gx && gyj == gy) { first = false; break; }
            }
            if (first) {
                float m  = 0.25f * (c0 + c1 + c2 + c3);
                float po = 1.0f / (1.0f + expf(-m));
                float inv = 1.0f / (float)(BS * hw);
                // (po-1)^2 - po^2 = 1 - 2*po
                acc += (1.0f / 3.0f) * (1.0f - 2.0f * po) * inv;
            }
        }
    }

    // ---- block reduction, one atomic per block ----
    __shared__ float sdata[4];
    #pragma unroll
    for (int off = 32; off > 0; off >>= 1)
        acc += __shfl_down(acc, off, 64);
    const int lane = threadIdx.x & 63;
    const int wid  = threadIdx.x >> 6;
    if (lane == 0) sdata[wid] = acc;
    __syncthreads();
    if (threadIdx.x == 0) {
        float t = sdata[0] + sdata[1] + sdata[2] + sdata[3];
        atomicAdd(out, t);
    }
}

extern "C" void kernel_launch(void* const* d_in, const int* in_sizes, int n_in,
                              void* d_out, int out_size, void* d_ws, size_t ws_size,
                              hipStream_t stream) {
    const float* p0  = (const float*)d_in[0];
    const float* p1  = (const float*)d_in[1];
    const float* p2  = (const float*)d_in[2];
    const float* gtb = (const float*)d_in[3];
    const int*   gtc = (const int*)d_in[4];
    float* out = (float*)d_out;

    hipMemsetAsync(out, 0, sizeof(float) * out_size, stream);

    const int total = BS * (80*80 + 40*40 + 20*20) + 3 * BS * NOBJ;  // 135936
    const int block = 256;
    const int grid  = (total + block - 1) / block;  // 531
    yolo_loss_kernel<<<grid, block, 0, stream>>>(p0, p1, p2, gtb, gtc, out);
}

// Round 2
// 27.183 us; speedup vs baseline: 2.3527x; 2.3527x over previous
//
#include <hip/hip_runtime.h>
#include <math.h>

#define NC   80
#define BS   16
#define NOBJ 32

__device__ __forceinline__ float softplusf(float x) {
    // stable log(1+exp(x)) == max(x,0) + log1p(exp(-|x|))  (matches jax.nn.softplus)
    return fmaxf(x, 0.0f) + log1pf(expf(-fabsf(x)));
}

__global__ void __launch_bounds__(256)
yolo_loss_kernel(const float* __restrict__ p0,
                 const float* __restrict__ p1,
                 const float* __restrict__ p2,
                 const float* __restrict__ gtb,   // (16,32,4) f32
                 const int*   __restrict__ gtc,   // (16,32) i32
                 float* __restrict__ out)
{
    const float* ps[3] = {p0, p1, p2};
    const int    hs[3] = {80, 40, 20};

    const int cells0 = BS * 80 * 80;                   // 102400
    const int cells1 = BS * 40 * 40;                   // 25600
    const int cells2 = BS * 20 * 20;                   // 6400
    const int totalCells = cells0 + cells1 + cells2;   // 134400
    const int nObjAll    = 3 * BS * NOBJ;              // 1536
    const int totalLcls  = nObjAll * NC;               // 122880
    const int total      = totalCells + totalLcls + nObjAll;  // 258816

    float acc = 0.0f;

    for (int i = blockIdx.x * blockDim.x + threadIdx.x; i < total;
         i += gridDim.x * blockDim.x) {
        if (i < totalCells) {
            // ---- lobj baseline over the whole grid (t = 0 everywhere) ----
            int idx = i, s;
            if (idx < cells0)                { s = 0; }
            else if (idx < cells0 + cells1)  { s = 1; idx -= cells0; }
            else                             { s = 2; idx -= cells0 + cells1; }
            const int h  = hs[s];
            const int hw = h * h;
            const int b  = idx / hw;
            const int r  = idx - b * hw;
            const float* p = ps[s];
            const size_t base = (size_t)b * 144 * hw + r;
            float m = 0.25f * (p[base] + p[base + hw] +
                               p[base + 2 * (size_t)hw] + p[base + 3 * (size_t)hw]);
            float po  = 1.0f / (1.0f + expf(-m));
            float inv = 1.0f / (float)(BS * hw);
            acc += (1.0f / 3.0f) * po * po * inv;
        } else if (i < totalCells + totalLcls) {
            // ---- lcls: one thread per (object, class channel) ----
            int t   = i - totalCells;
            int oi  = t / NC;                // global object index [0,1536)
            int c   = t - oi * NC;           // class channel [0,80)
            int s   = oi / (BS * NOBJ);
            int rem = oi - s * (BS * NOBJ);
            int b   = rem / NOBJ;
            int o   = rem - b * NOBJ;
            const int h  = hs[s];
            const int w  = h;
            const int hw = h * w;
            const float* p = ps[s];
            const float* g = gtb + ((size_t)b * NOBJ + o) * 4;
            int gx = min(max((int)(g[0] * w), 0), w - 1);
            int gy = min(max((int)(g[1] * h), 0), h - 1);
            const size_t cell = (size_t)b * 144 * hw + (size_t)gy * w + gx;
            float x = p[cell + (size_t)(64 + c) * hw];
            float lc = softplusf(x);
            if (c == gtc[b * NOBJ + o]) lc -= x;
            acc += (0.5f / 3.0f) * (1.0f / (float)NC) * lc;
        } else {
            // ---- per-object: lbox + lobj correction at marked cells ----
            int oi  = i - totalCells - totalLcls;
            int s   = oi / (BS * NOBJ);
            int rem = oi - s * (BS * NOBJ);
            int b   = rem / NOBJ;
            int o   = rem - b * NOBJ;
            const int h  = hs[s];
            const int w  = h;
            const int hw = h * w;
            const float* p = ps[s];
            const float* g = gtb + ((size_t)b * NOBJ + o) * 4;
            float cx = g[0] * w, cy = g[1] * h, gw = g[2] * w, gh = g[3] * h;
            int gx = min(max((int)cx, 0), w - 1);
            int gy = min(max((int)cy, 0), h - 1);
            const size_t cell = (size_t)b * 144 * hw + (size_t)gy * w + gx;

            // lbox: mean over 4 of (pred - target)^2
            float bt0 = cx - (float)gx;
            float bt1 = cy - (float)gy;
            float bt2 = gw / (float)w;
            float bt3 = gh / (float)h;
            float c0 = p[cell];
            float c1 = p[cell + hw];
            float c2 = p[cell + 2 * (size_t)hw];
            float c3 = p[cell + 3 * (size_t)hw];
            float d0 = c0 - bt0, d1 = c1 - bt1, d2 = c2 - bt2, d3 = c3 - bt3;
            acc += (7.5f / 3.0f) * 0.25f * (d0*d0 + d1*d1 + d2*d2 + d3*d3);

            // lobj correction: only the FIRST object hitting this cell counts
            // (reference .set(1.0) scatter is idempotent across duplicates)
            bool first = true;
            for (int j = 0; j < o; ++j) {
                const float* gj = gtb + ((size_t)b * NOBJ + j) * 4;
                int gxj = min(max((int)(gj[0] * w), 0), w - 1);
                int gyj = min(max((int)(gj[1] * h), 0), h - 1);
                if (gxj == gx && gyj == gy) { first = false; break; }
            }
            if (first) {
                float m  = 0.25f * (c0 + c1 + c2 + c3);
                float po = 1.0f / (1.0f + expf(-m));
                float inv = 1.0f / (float)(BS * hw);
                // (po-1)^2 - po^2 = 1 - 2*po
                acc += (1.0f / 3.0f) * (1.0f - 2.0f * po) * inv;
            }
        }
    }

    // ---- block reduction, one atomic per block ----
    __shared__ float sdata[4];
    #pragma unroll
    for (int off = 32; off > 0; off >>= 1)
        acc += __shfl_down(acc, off, 64);
    const int lane = threadIdx.x & 63;
    const int wid  = threadIdx.x >> 6;
    if (lane == 0) sdata[wid] = acc;
    __syncthreads();
    if (threadIdx.x == 0) {
        float t = sdata[0] + sdata[1] + sdata[2] + sdata[3];
        atomicAdd(out, t);
    }
}

extern "C" void kernel_launch(void* const* d_in, const int* in_sizes, int n_in,
                              void* d_out, int out_size, void* d_ws, size_t ws_size,
                              hipStream_t stream) {
    const float* p0  = (const float*)d_in[0];
    const float* p1  = (const float*)d_in[1];
    const float* p2  = (const float*)d_in[2];
    const float* gtb = (const float*)d_in[3];
    const int*   gtc = (const int*)d_in[4];
    float* out = (float*)d_out;

    hipMemsetAsync(out, 0, sizeof(float) * out_size, stream);

    const int total = BS * (80*80 + 40*40 + 20*20)       // cells
                    + 3 * BS * NOBJ * NC                 // lcls items
                    + 3 * BS * NOBJ;                     // box items
    const int block = 256;
    const int grid  = (total + block - 1) / block;       // 1011
    yolo_loss_kernel<<<grid, block, 0, stream>>>(p0, p1, p2, gtb, gtc, out);
}

// Round 3
// 13.416 us; speedup vs baseline: 4.7672x; 2.0263x over previous
//
#include <hip/hip_runtime.h>
#include <math.h>

#define NC   80
#define BS   16
#define NOBJ 32

__device__ __forceinline__ float softplusf(float x) {
    // stable log(1+exp(x)) == max(x,0) + log1p(exp(-|x|))  (matches jax.nn.softplus)
    return fmaxf(x, 0.0f) + log1pf(expf(-fabsf(x)));
}

// 4 consecutive cells (one float4 per plane) of the lobj baseline, scale H
template<int H>
__device__ __forceinline__ float cell_quad(const float* __restrict__ p, int idx) {
    constexpr int HW = H * H;
    constexpr int Q  = HW / 4;          // float4s per plane
    int b = idx / Q;                    // compile-time divisor -> magic mul
    int r = idx - b * Q;
    const float4* pl = (const float4*)(p + (size_t)b * 144 * HW);
    float4 a0 = pl[r];
    float4 a1 = pl[r + Q];
    float4 a2 = pl[r + 2 * Q];
    float4 a3 = pl[r + 3 * Q];
    constexpr float inv = 1.0f / (float)(BS * HW);
    float sum = 0.0f, m, po;
    m = 0.25f * (a0.x + a1.x + a2.x + a3.x); po = 1.0f/(1.0f+expf(-m)); sum += po*po;
    m = 0.25f * (a0.y + a1.y + a2.y + a3.y); po = 1.0f/(1.0f+expf(-m)); sum += po*po;
    m = 0.25f * (a0.z + a1.z + a2.z + a3.z); po = 1.0f/(1.0f+expf(-m)); sum += po*po;
    m = 0.25f * (a0.w + a1.w + a2.w + a3.w); po = 1.0f/(1.0f+expf(-m)); sum += po*po;
    return (1.0f / 3.0f) * inv * sum;
}

__global__ void __launch_bounds__(256)
yolo_loss_main(const float* __restrict__ p0,
               const float* __restrict__ p1,
               const float* __restrict__ p2,
               const float* __restrict__ gtb,   // (16,32,4) f32
               const int*   __restrict__ gtc,   // (16,32) i32
               float* __restrict__ partials)
{
    constexpr int q0 = BS * 80 * 80 / 4;               // 25600
    constexpr int q1 = BS * 40 * 40 / 4;               // 6400
    constexpr int q2 = BS * 20 * 20 / 4;               // 1600
    constexpr int totalQuads = q0 + q1 + q2;           // 33600
    constexpr int nObjAll    = 3 * BS * NOBJ;          // 1536
    constexpr int totalLcls  = nObjAll * NC;           // 122880
    constexpr int total      = totalQuads + totalLcls + nObjAll;  // 158016

    float acc = 0.0f;

    for (int i = blockIdx.x * blockDim.x + threadIdx.x; i < total;
         i += gridDim.x * blockDim.x) {
        if (i < totalQuads) {
            if (i < q0)           acc += cell_quad<80>(p0, i);
            else if (i < q0 + q1) acc += cell_quad<40>(p1, i - q0);
            else                  acc += cell_quad<20>(p2, i - q0 - q1);
        } else if (i < totalQuads + totalLcls) {
            // ---- lcls: one thread per (object, class channel) ----
            int t   = i - totalQuads;
            int oi  = t / NC;                 // const divisors throughout
            int c   = t - oi * NC;
            int s   = oi / (BS * NOBJ);
            int rem = oi - s * (BS * NOBJ);
            int b   = rem / NOBJ;
            int o   = rem - b * NOBJ;
            int w   = (s == 0) ? 80 : ((s == 1) ? 40 : 20);
            int hw  = w * w;
            const float* p = (s == 0) ? p0 : ((s == 1) ? p1 : p2);
            const float* g = gtb + ((size_t)b * NOBJ + o) * 4;
            int gx = min(max((int)(g[0] * w), 0), w - 1);
            int gy = min(max((int)(g[1] * w), 0), w - 1);
            const size_t cell = (size_t)b * 144 * hw + (size_t)gy * w + gx;
            float x = p[cell + (size_t)(64 + c) * hw];
            float lc = softplusf(x);
            if (c == gtc[b * NOBJ + o]) lc -= x;
            acc += (0.5f / 3.0f) * (1.0f / (float)NC) * lc;
        } else {
            // ---- per-object: lbox + lobj correction at marked cells ----
            int oi  = i - totalQuads - totalLcls;
            int s   = oi / (BS * NOBJ);
            int rem = oi - s * (BS * NOBJ);
            int b   = rem / NOBJ;
            int o   = rem - b * NOBJ;
            int w   = (s == 0) ? 80 : ((s == 1) ? 40 : 20);
            int hw  = w * w;
            const float* p = (s == 0) ? p0 : ((s == 1) ? p1 : p2);
            const float* g = gtb + ((size_t)b * NOBJ + o) * 4;
            float cx = g[0] * w, cy = g[1] * w, gw = g[2] * w, gh = g[3] * w;
            int gx = min(max((int)cx, 0), w - 1);
            int gy = min(max((int)cy, 0), w - 1);
            const size_t cell = (size_t)b * 144 * hw + (size_t)gy * w + gx;

            float bt0 = cx - (float)gx;
            float bt1 = cy - (float)gy;
            float bt2 = gw / (float)w;
            float bt3 = gh / (float)w;
            float c0 = p[cell];
            float c1 = p[cell + hw];
            float c2 = p[cell + 2 * (size_t)hw];
            float c3 = p[cell + 3 * (size_t)hw];
            float d0 = c0 - bt0, d1 = c1 - bt1, d2 = c2 - bt2, d3 = c3 - bt3;
            acc += (7.5f / 3.0f) * 0.25f * (d0*d0 + d1*d1 + d2*d2 + d3*d3);

            // lobj correction: only the FIRST object mapping to this cell
            bool first = true;
            for (int j = 0; j < o; ++j) {
                const float* gj = gtb + ((size_t)b * NOBJ + j) * 4;
                int gxj = min(max((int)(gj[0] * w), 0), w - 1);
                int gyj = min(max((int)(gj[1] * w), 0), w - 1);
                if (gxj == gx && gyj == gy) { first = false; break; }
            }
            if (first) {
                float m  = 0.25f * (c0 + c1 + c2 + c3);
                float po = 1.0f / (1.0f + expf(-m));
                float inv = 1.0f / (float)(BS * hw);
                acc += (1.0f / 3.0f) * (1.0f - 2.0f * po) * inv;  // (po-1)^2 - po^2
            }
        }
    }

    // ---- block reduction -> one partial per block (plain store, no zeroing) ----
    __shared__ float sdata[4];
    #pragma unroll
    for (int off = 32; off > 0; off >>= 1)
        acc += __shfl_down(acc, off, 64);
    const int lane = threadIdx.x & 63;
    const int wid  = threadIdx.x >> 6;
    if (lane == 0) sdata[wid] = acc;
    __syncthreads();
    if (threadIdx.x == 0)
        partials[blockIdx.x] = sdata[0] + sdata[1] + sdata[2] + sdata[3];
}

__global__ void __launch_bounds__(256)
yolo_loss_reduce(const float* __restrict__ partials, int n, float* __restrict__ out)
{
    float acc = 0.0f;
    for (int i = threadIdx.x; i < n; i += 256) acc += partials[i];
    __shared__ float sdata[4];
    #pragma unroll
    for (int off = 32; off > 0; off >>= 1)
        acc += __shfl_down(acc, off, 64);
    const int lane = threadIdx.x & 63;
    const int wid  = threadIdx.x >> 6;
    if (lane == 0) sdata[wid] = acc;
    __syncthreads();
    if (threadIdx.x == 0)
        out[0] = sdata[0] + sdata[1] + sdata[2] + sdata[3];
}

extern "C" void kernel_launch(void* const* d_in, const int* in_sizes, int n_in,
                              void* d_out, int out_size, void* d_ws, size_t ws_size,
                              hipStream_t stream) {
    const float* p0  = (const float*)d_in[0];
    const float* p1  = (const float*)d_in[1];
    const float* p2  = (const float*)d_in[2];
    const float* gtb = (const float*)d_in[3];
    const int*   gtc = (const int*)d_in[4];
    float* out      = (float*)d_out;
    float* partials = (float*)d_ws;

    const int total = (BS * (80*80 + 40*40 + 20*20)) / 4   // cell quads
                    + 3 * BS * NOBJ * NC                   // lcls items
                    + 3 * BS * NOBJ;                       // box items
    const int block = 256;
    const int grid  = (total + block - 1) / block;         // 618

    yolo_loss_main<<<grid, block, 0, stream>>>(p0, p1, p2, gtb, gtc, partials);
    yolo_loss_reduce<<<1, block, 0, stream>>>(partials, grid, out);
}